// Round 9
// baseline (442.693 us; speedup 1.0000x reference)
//
#include <hip/hip_runtime.h>

typedef unsigned short u16;
typedef unsigned int   u32;

typedef __attribute__((ext_vector_type(8))) short s16x8;   // 8 bf16 (4 VGPRs)
typedef __attribute__((ext_vector_type(4))) float f32x4;

// ---------- bf16 helpers (internal staging only; d_in/d_out are FLOAT32) ----------
__device__ __forceinline__ float bf2f(u16 u){
  union { u32 i; float f; } v; v.i = ((u32)u) << 16; return v.f;
}
__device__ __forceinline__ u16 f2bf(float f){
  union { float f; u32 i; } v; v.f = f;
  u32 x = v.i;
  return (u16)((x + 0x7fffu + ((x >> 16) & 1u)) >> 16);   // RNE
}

// Geometry: b=8, C=64, H=W=128, f=4 -> 128 attention blocks of n=1024 tokens, E=64.
// Activations between attn and output use channel-last PADDED layout:
//   [b][hp=h+2 (132)][wp=w+2 (132)][ci 64]  (borders zeroed -> no conv bounds checks)

// ---------- K1: per-batch LayerNorm stats (sum, sumsq) ----------
__global__ __launch_bounds__(256) void k_lnstats(const float* __restrict__ x, float* __restrict__ stats){
  const int bb    = blockIdx.x >> 7;      // batch
  const int chunk = blockIdx.x & 127;     // 128 chunks of 8192 elems
  const float4* p = (const float4*)(x + bb*1048576 + chunk*8192);
  float s = 0.f, ss = 0.f;
  #pragma unroll
  for (int i=0;i<8;++i){
    float4 v = p[threadIdx.x + (i<<8)];
    s  += v.x + v.y + v.z + v.w;
    ss += v.x*v.x + v.y*v.y + v.z*v.z + v.w*v.w;
  }
  #pragma unroll
  for (int off=32; off; off>>=1){ s += __shfl_down(s, off); ss += __shfl_down(ss, off); }
  __shared__ float rs[4], rss[4];
  const int lane = threadIdx.x & 63, wv = threadIdx.x >> 6;
  if (lane == 0){ rs[wv] = s; rss[wv] = ss; }
  __syncthreads();
  if (threadIdx.x == 0){
    atomicAdd(&stats[bb*2+0], rs[0]+rs[1]+rs[2]+rs[3]);
    atomicAdd(&stats[bb*2+1], rss[0]+rss[1]+rss[2]+rss[3]);
  }
}

// ---------- K1b: weight transform w[co][ci][3][3] f32 -> wt[tap][co][ci] bf16 ----------
__global__ __launch_bounds__(256) void k_wt(const float* __restrict__ w, u16* __restrict__ wt){
  int e = blockIdx.x*256 + threadIdx.x;   // grid 144 -> 36864 elems
  int tap = e >> 12, co = (e >> 6) & 63, ci = e & 63;
  wt[e] = f2bf(w[(co*64 + ci)*9 + tap]);
}

// ---------- K2: gather tokens, LN, q = normalize(xx @ wqk), v gather (v stored [Bb][ch][token]) ----------
__global__ __launch_bounds__(256) void k_qv(const float* __restrict__ x, const float* __restrict__ wqk,
                                            const float* __restrict__ stats,
                                            u16* __restrict__ qb, u16* __restrict__ vb){
  const int Bb = blockIdx.x >> 4;          // 0..127
  const int mt = blockIdx.x & 15;          // token tile (64 tokens)
  const int b = Bb >> 4, fi = (Bb >> 2) & 3, fj = Bb & 3;
  const float inv_n = 1.f/1048576.f;
  const float mu   = stats[2*b] * inv_n;
  const float var  = stats[2*b+1]*inv_n - mu*mu;
  const float rstd = rsqrtf(var + 1e-5f);

  __shared__ float xt[64][68];             // [token][cc], normalized
  __shared__ float wk[64][68];             // [cc][e]  (later reused for v staging)
  __shared__ float red[64][17];
  const int t = threadIdx.x;
  const int m0 = mt << 6;

  #pragma unroll
  for (int i=0;i<16;++i){ int e = t+(i<<8); wk[e>>6][e&63] = wqk[e]; }
  #pragma unroll
  for (int i=0;i<16;++i){
    int e = t+(i<<8); int cc = e>>6, ml = e&63;
    int m = m0 + ml;
    int hh = ((m>>5)<<2)+fi, ww = ((m&31)<<2)+fj;
    xt[ml][cc] = (x[(((b<<6)+cc)<<14)+(hh<<7)+ww] - mu)*rstd;
  }
  __syncthreads();                         // [A]

  const int ty = t>>4, tx = t&15;
  float acc[4][4] = {};
  for (int cc=0; cc<64; ++cc){
    float a0=xt[(ty<<2)+0][cc], a1=xt[(ty<<2)+1][cc], a2=xt[(ty<<2)+2][cc], a3=xt[(ty<<2)+3][cc];
    float b0=wk[cc][(tx<<2)+0], b1=wk[cc][(tx<<2)+1], b2=wk[cc][(tx<<2)+2], b3=wk[cc][(tx<<2)+3];
    acc[0][0]+=a0*b0; acc[0][1]+=a0*b1; acc[0][2]+=a0*b2; acc[0][3]+=a0*b3;
    acc[1][0]+=a1*b0; acc[1][1]+=a1*b1; acc[1][2]+=a1*b2; acc[1][3]+=a1*b3;
    acc[2][0]+=a2*b0; acc[2][1]+=a2*b1; acc[2][2]+=a2*b2; acc[2][3]+=a2*b3;
    acc[3][0]+=a3*b0; acc[3][1]+=a3*b1; acc[3][2]+=a3*b2; acc[3][3]+=a3*b3;
  }
  #pragma unroll
  for (int i=0;i<4;++i){
    float pn = acc[i][0]*acc[i][0]+acc[i][1]*acc[i][1]+acc[i][2]*acc[i][2]+acc[i][3]*acc[i][3];
    red[(ty<<2)+i][tx] = pn;
  }
  __syncthreads();                         // [B] -- all acc/xt reads done
  float inv[4];
  #pragma unroll
  for (int i=0;i<4;++i){
    float s = 0.f;
    #pragma unroll
    for (int k=0;k<16;++k) s += red[(ty<<2)+i][k];
    inv[i] = 1.f / fmaxf(sqrtf(s), 1e-12f);
  }
  // stage normalized q back into xt (safe after [B])
  #pragma unroll
  for (int i=0;i<4;++i)
    #pragma unroll
    for (int j=0;j<4;++j)
      xt[(ty<<2)+i][(tx<<2)+j] = acc[i][j]*inv[i];
  __syncthreads();                         // [C]
  #pragma unroll
  for (int i=0;i<16;++i){
    int e = t+(i<<8); int ml = e>>6, ee = e&63;
    qb[((Bb<<10)+m0+ml)*64 + ee] = f2bf(xt[ml][ee]);
  }
  // v gather -> wk (safe after [B]/[C]); write out TRANSPOSED: vb[Bb][ch][token]
  #pragma unroll
  for (int i=0;i<16;++i){
    int e = t+(i<<8); int cc = e>>6, ml = e&63;
    int m = m0 + ml;
    int hh = ((m>>5)<<2)+fi, ww = ((m&31)<<2)+fj;
    wk[ml][cc] = x[(((b<<6)+cc)<<14)+(hh<<7)+ww];
  }
  __syncthreads();                         // [D]
  #pragma unroll
  for (int i=0;i<16;++i){
    int e = t+(i<<8); int cc = e>>6, ml = e&63;      // token-fastest for coalesced store
    vb[(Bb<<16) + (cc<<10) + m0 + ml] = f2bf(wk[ml][cc]);
  }
}

// ---------- K3: flash attention via MFMA 16x16x32 bf16, 2 q-tiles/block, XCD-swizzled ----------
// bid = ((qtp*16 + sub)*8) + b  ->  bid%8 = batch  (one batch per XCD: K/V+x L2-resident)
__global__ __launch_bounds__(256) void k_attn(const u16* __restrict__ qb, const u16* __restrict__ vb,
                                              const float* __restrict__ x, u16* __restrict__ apad){
  const int bid = blockIdx.x;              // 0..1023
  const int b   = bid & 7;
  const int rem = bid >> 3;                // 0..127
  const int qtp = rem >> 4;                // 0..7  (pair of q-tiles)
  const int sub = rem & 15;
  const int Bb  = (b<<4) + sub;
  const int fi = (sub>>2)&3, fj = sub&3;
  const int qt0 = qtp << 1;
  __shared__ __align__(16) char lds[24576];
  const int KS = 0, VS = 8192, PS = 16384;

  const int t = threadIdx.x;
  const int w = t >> 6, lane = t & 63;
  const int lrow = lane & 15, lk = lane >> 4;

  const u16* qB = qb + (Bb<<16);
  const u16* vB = vb + (Bb<<16);

  // Q fragments for this wave's rows in both q-tiles
  s16x8 qf[2][2];
  #pragma unroll
  for (int t2=0; t2<2; ++t2){
    const u16* qrp = qB + (((qt0+t2)<<6) + (w<<4) + lrow)*64;
    qf[t2][0] = *(const s16x8*)(qrp + (lk<<3));
    qf[t2][1] = *(const s16x8*)(qrp + 32 + (lk<<3));
  }

  f32x4 o_acc[2][4] = {};
  float lp[2][4] = {};

  for (int kt=0; kt<16; ++kt){
    __syncthreads();
    #pragma unroll
    for (int c = t; c < 512; c += 256){
      int row = c >> 3, slot = c & 7;
      uint4 kv = *(const uint4*)(qB + ((kt<<6)+row)*64 + (slot<<3));
      *(uint4*)(lds + KS + row*128 + (((slot ^ (row&7)))<<4)) = kv;
      uint4 vv = *(const uint4*)(vB + (row<<10) + (kt<<6) + (slot<<3));
      *(uint4*)(lds + VS + row*128 + (((slot ^ (row&7)))<<4)) = vv;
    }
    __syncthreads();

    #pragma unroll
    for (int t2=0; t2<2; ++t2){
      // S = Q K^T
      f32x4 s_acc[4] = {};
      #pragma unroll
      for (int nt=0; nt<4; ++nt){
        int key = (nt<<4) + lrow;
        const char* kb = lds + KS + key*128;
        s16x8 kf0 = *(const s16x8*)(kb + ((lk       ^ (key&7))<<4));
        s16x8 kf1 = *(const s16x8*)(kb + (((4+lk)   ^ (key&7))<<4));
        s_acc[nt] = __builtin_amdgcn_mfma_f32_16x16x32_bf16(qf[t2][0], kf0, s_acc[nt], 0,0,0);
        s_acc[nt] = __builtin_amdgcn_mfma_f32_16x16x32_bf16(qf[t2][1], kf1, s_acc[nt], 0,0,0);
      }
      // P = exp(S/8) -> per-wave LDS strip (bf16), same-wave produce/consume
      #pragma unroll
      for (int nt=0; nt<4; ++nt)
        #pragma unroll
        for (int r=0; r<4; ++r){
          float p = __expf(s_acc[nt][r]*0.125f);
          lp[t2][r] += p;
          int prow = (w<<4) + (lk<<2) + r;
          int key  = (nt<<4) + lrow;
          *(u16*)(lds + PS + prow*128 + ((key<<1) ^ ((prow&7)<<4))) = f2bf(p);
        }
      // O += P V
      {
        int prow = (w<<4) + lrow;
        const char* pb = lds + PS + prow*128;
        s16x8 pf0 = *(const s16x8*)(pb + ((lk     ^ (prow&7))<<4));
        s16x8 pf1 = *(const s16x8*)(pb + (((4+lk) ^ (prow&7))<<4));
        #pragma unroll
        for (int nt=0; nt<4; ++nt){
          int ch = (nt<<4) + lrow;
          const char* vbp = lds + VS + ch*128;
          s16x8 vf0 = *(const s16x8*)(vbp + ((lk     ^ (ch&7))<<4));
          s16x8 vf1 = *(const s16x8*)(vbp + (((4+lk) ^ (ch&7))<<4));
          o_acc[t2][nt] = __builtin_amdgcn_mfma_f32_16x16x32_bf16(pf0, vf0, o_acc[t2][nt], 0,0,0);
          o_acc[t2][nt] = __builtin_amdgcn_mfma_f32_16x16x32_bf16(pf1, vf1, o_acc[t2][nt], 0,0,0);
        }
      }
    }
  }

  // row sums -> 1/l  (reduce across the 16 lanes sharing lk)
  #pragma unroll
  for (int t2=0; t2<2; ++t2)
    #pragma unroll
    for (int r=0;r<4;++r){
      float s = lp[t2][r];
      s += __shfl_xor(s, 1); s += __shfl_xor(s, 2);
      s += __shfl_xor(s, 4); s += __shfl_xor(s, 8);
      lp[t2][r] = 1.f / s;
    }

  float* os = (float*)lds;                 // reuse lds as os[64][68] f32 per tile
  #pragma unroll
  for (int t2=0; t2<2; ++t2){
    __syncthreads();                       // t2=0: ks/vs/ps reads done; t2=1: prev os reads done
    #pragma unroll
    for (int nt=0; nt<4; ++nt)
      #pragma unroll
      for (int r=0; r<4; ++r)
        os[((w<<4)+(lk<<2)+r)*68 + (nt<<4)+lrow] = o_acc[t2][nt][r]*lp[t2][r];
    __syncthreads();
    const int m0 = (qt0+t2) << 6;
    // phase 1: residual add (gather pattern proven in r4/r7)
    #pragma unroll
    for (int i=0;i<16;++i){
      int e = t+(i<<8);
      int cc = e>>6, ml = e&63;
      int m = m0 + ml;
      int hh = ((m>>5)<<2)+fi, ww = ((m&31)<<2)+fj;
      os[ml*68 + cc] += x[(((b<<6)+cc)<<14) + (hh<<7) + ww];
    }
    __syncthreads();
    // phase 2: coalesced channel-last padded write
    #pragma unroll
    for (int i=0;i<16;++i){
      int e = t+(i<<8);
      int ml = e>>6, cc = e&63;
      int m = m0 + ml;
      int hh = ((m>>5)<<2)+fi, ww = ((m&31)<<2)+fj;
      apad[((b*132 + hh+2)*132 + ww+2)*64 + cc] = f2bf(os[ml*68 + cc]);
    }
  }
}

// ---------- K4/K5: 3x3 dil-2 conv via MFMA implicit GEMM, channel-last padded, no LDS ----------
// 1D grid 2048, bid%8 = batch (XCD-swizzled: each batch's input L2-resident on one XCD).
__global__ __launch_bounds__(256) void k_conv3m(const u16* __restrict__ in, const u16* __restrict__ wt,
                                                const float* __restrict__ bias, u16* __restrict__ outp){
  const int bid = blockIdx.x;
  const int b   = bid & 7;
  const int r   = bid >> 3;                // 0..255
  const int h   = r & 127;
  const int seg = r >> 7;                  // 0..1
  const int t = threadIdx.x;
  const int wv = t >> 6, lane = t & 63;
  const int lrow = lane & 15, lk = lane >> 4;
  const int co0 = wv << 4;
  const int w0 = seg << 6;

  s16x8 A[9][2];
  #pragma unroll
  for (int tap=0; tap<9; ++tap)
    #pragma unroll
    for (int hf=0; hf<2; ++hf)
      A[tap][hf] = *(const s16x8*)(wt + (((tap<<6) + co0 + lrow)<<6) + (hf<<5) + (lk<<3));

  float4 b4 = *(const float4*)&bias[co0 + (lk<<2)];
  f32x4 binit = {b4.x, b4.y, b4.z, b4.w};
  f32x4 acc[4] = {binit, binit, binit, binit};

  const int base_b = b * (132*132);        // pixel-index base
  #pragma unroll
  for (int dh=0; dh<3; ++dh){
    const u16* rowp = in + ((base_b + (h + (dh<<1))*132)<<6);
    #pragma unroll
    for (int dw=0; dw<3; ++dw){
      #pragma unroll
      for (int hf=0; hf<2; ++hf){
        #pragma unroll
        for (int pt=0; pt<4; ++pt){
          int wp = w0 + (pt<<4) + lrow + (dw<<1);
          s16x8 B = *(const s16x8*)(rowp + (wp<<6) + (hf<<5) + (lk<<3));
          acc[pt] = __builtin_amdgcn_mfma_f32_16x16x32_bf16(A[dh*3+dw][hf], B, acc[pt], 0,0,0);
        }
      }
    }
  }

  #pragma unroll
  for (int pt=0; pt<4; ++pt){
    int wp = w0 + (pt<<4) + lrow + 2;
    u16* op = outp + ((base_b + (h+2)*132 + wp)<<6) + co0 + (lk<<2);
    ushort4 o4;
    o4.x = f2bf(fmaxf(acc[pt][0], 0.f));
    o4.y = f2bf(fmaxf(acc[pt][1], 0.f));
    o4.z = f2bf(fmaxf(acc[pt][2], 0.f));
    o4.w = f2bf(fmaxf(acc[pt][3], 0.f));
    *(ushort4*)op = o4;
  }
}

// ---------- K6: 1x1 conv + residual with x (y2 padded ch-last in, f32 out) ----------
__global__ __launch_bounds__(256) void k_conv1x1(const u16* __restrict__ y2, const float* __restrict__ w3,
                                                 const float* __restrict__ b3, const float* __restrict__ x,
                                                 float* __restrict__ out){
  const int b  = blockIdx.x >> 6;
  const int p0 = (blockIdx.x & 63) << 8;   // 256 pixels per block
  __shared__ u16  ys[256][68];             // [px][ci]
  __shared__ float w3s[64][68];            // [ci][co]
  __shared__ float bs[64];
  const int t = threadIdx.x;
  #pragma unroll
  for (int i=0;i<16;++i){ int e = t+(i<<8); w3s[e & 63][e >> 6] = w3[e]; }
  if (t < 64) bs[t] = b3[t];
  #pragma unroll
  for (int i=0;i<64;++i){
    int e = t + (i<<8);
    int px = e >> 6, ci = e & 63;
    int pg = p0 + px; int hh = pg >> 7, ww = pg & 127;
    ys[px][ci] = y2[((b*132 + hh+2)*132 + ww+2)*64 + ci];
  }
  __syncthreads();
  const int cog = (t >> 6) << 4;           // co base: 0/16/32/48 (uniform per wave)
  const int pl  = t & 63;                  // pixels pl, pl+64, pl+128, pl+192
  float acc[16][4];
  #pragma unroll
  for (int c=0;c<16;++c){
    float bvv = bs[cog+c];
    acc[c][0]=bvv; acc[c][1]=bvv; acc[c][2]=bvv; acc[c][3]=bvv;
  }
  for (int c4=0;c4<64;c4+=4){
    float yv[4][4];
    #pragma unroll
    for (int p=0;p<4;++p){
      ushort4 u = *(const ushort4*)&ys[pl + (p<<6)][c4];
      yv[p][0]=bf2f(u.x); yv[p][1]=bf2f(u.y); yv[p][2]=bf2f(u.z); yv[p][3]=bf2f(u.w);
    }
    #pragma unroll
    for (int cq=0;cq<4;++cq){
      float4 w0 = *(const float4*)&w3s[c4+0][cog+(cq<<2)];
      float4 w1 = *(const float4*)&w3s[c4+1][cog+(cq<<2)];
      float4 w2 = *(const float4*)&w3s[c4+2][cog+(cq<<2)];
      float4 w3v = *(const float4*)&w3s[c4+3][cog+(cq<<2)];
      #pragma unroll
      for (int p=0;p<4;++p){
        acc[(cq<<2)+0][p] += yv[p][0]*w0.x + yv[p][1]*w1.x + yv[p][2]*w2.x + yv[p][3]*w3v.x;
        acc[(cq<<2)+1][p] += yv[p][0]*w0.y + yv[p][1]*w1.y + yv[p][2]*w2.y + yv[p][3]*w3v.y;
        acc[(cq<<2)+2][p] += yv[p][0]*w0.z + yv[p][1]*w1.z + yv[p][2]*w2.z + yv[p][3]*w3v.z;
        acc[(cq<<2)+3][p] += yv[p][0]*w0.w + yv[p][1]*w1.w + yv[p][2]*w2.w + yv[p][3]*w3v.w;
      }
    }
  }
  #pragma unroll
  for (int c=0;c<16;++c){
    int base = (((b<<6)+cog+c)<<14) + p0 + pl;
    #pragma unroll
    for (int p=0;p<4;++p){
      int gi = base + (p<<6);
      out[gi] = acc[c][p] + x[gi];
    }
  }
}

// ---------- launch ----------
extern "C" void kernel_launch(void* const* d_in, const int* in_sizes, int n_in,
                              void* d_out, int out_size, void* d_ws, size_t ws_size,
                              hipStream_t stream){
  const float* x   = (const float*)d_in[0];
  const float* wqk = (const float*)d_in[1];
  const float* w1  = (const float*)d_in[2];
  const float* b1  = (const float*)d_in[3];
  const float* w2  = (const float*)d_in[4];
  const float* b2  = (const float*)d_in[5];
  const float* w3  = (const float*)d_in[6];
  const float* b3  = (const float*)d_in[7];
  float* out = (float*)d_out;

  // ws layout (51.5 MB):
  //   stats 256B | qb 16MB | vb 16MB | apad 17.84MB | wt1 72KB | wt2 72KB
  //   y1 aliases qb+vb (dead after attn); y2 aliases apad (a dead after conv1)
  float* stats = (float*)d_ws;
  u16* qb   = (u16*)((char*)d_ws + 256);
  u16* vb   = qb + 8388608;
  u16* apad = vb + 8388608;                // 8*132*132*64 = 8,921,088 elems
  u16* y1   = qb;
  u16* y2   = apad;
  u16* wt1  = apad + 8921088;
  u16* wt2  = wt1 + 36864;

  hipMemsetAsync(stats, 0, 64, stream);
  k_wt<<<144, 256, 0, stream>>>(w1, wt1);
  k_wt<<<144, 256, 0, stream>>>(w2, wt2);
  k_lnstats<<<1024, 256, 0, stream>>>(x, stats);
  k_qv     <<<2048, 256, 0, stream>>>(x, wqk, stats, qb, vb);
  hipMemsetAsync(apad, 0, 17842176, stream);                    // zero a borders
  k_attn   <<<1024, 256, 0, stream>>>(qb, vb, x, apad);
  hipMemsetAsync(y1, 0, 17842176, stream);                      // zero y1 borders (qb/vb dead)
  k_conv3m <<<2048, 256, 0, stream>>>(apad, wt1, b1, y1);
  k_conv3m <<<2048, 256, 0, stream>>>(y1, wt2, b2, y2);         // y2 = apad region
  k_conv1x1<<<512, 256, 0, stream>>>(y2, w3, b3, x, out);
}

// Round 11
// 394.577 us; speedup vs baseline: 1.1219x; 1.1219x over previous
//
#include <hip/hip_runtime.h>

typedef unsigned short u16;
typedef unsigned int   u32;

typedef __attribute__((ext_vector_type(8))) short s16x8;   // 8 bf16 (4 VGPRs)
typedef __attribute__((ext_vector_type(4))) float f32x4;
typedef __attribute__((ext_vector_type(4))) u32   u32x4;

// ---------- bf16 helpers (internal staging only; d_in/d_out are FLOAT32) ----------
__device__ __forceinline__ float bf2f(u16 u){
  union { u32 i; float f; } v; v.i = ((u32)u) << 16; return v.f;
}
__device__ __forceinline__ u16 f2bf(float f){
  union { float f; u32 i; } v; v.f = f;
  u32 x = v.i;
  return (u16)((x + 0x7fffu + ((x >> 16) & 1u)) >> 16);   // RNE
}
__device__ __forceinline__ s16x8 as_s16x8(u32x4 v){ return __builtin_bit_cast(s16x8, v); }

// Geometry: b=8, C=64, H=W=128, f=4 -> 128 attention blocks of n=1024 tokens, E=64.
// Activations between attn and output use channel-last PADDED layout:
//   [b][hp=h+2 (132)][wp=w+2 (132)][ci 64]  (borders zeroed -> no conv bounds checks)
// vb is stored with sigma-permuted token order within each 64-token tile so that
// in-register P (from transposed QK^T) and LDS V feed the PV MFMA with identical
// (slot,j)->key maps:  sigma(k): nt=k>>4, ss=(k>>2)&3, r=k&3 ->
//   sigma = ((ss + ((nt>>1)<<2))<<3) + ((nt&1)<<2) + r   (verified: sigma(kappa(s,j))=8s+j)

// ---------- K1: per-batch LayerNorm stats (sum, sumsq) ----------
__global__ __launch_bounds__(256) void k_lnstats(const float* __restrict__ x, float* __restrict__ stats){
  const int bb    = blockIdx.x >> 7;      // batch
  const int chunk = blockIdx.x & 127;     // 128 chunks of 8192 elems
  const float4* p = (const float4*)(x + bb*1048576 + chunk*8192);
  float s = 0.f, ss = 0.f;
  #pragma unroll
  for (int i=0;i<8;++i){
    float4 v = p[threadIdx.x + (i<<8)];
    s  += v.x + v.y + v.z + v.w;
    ss += v.x*v.x + v.y*v.y + v.z*v.z + v.w*v.w;
  }
  #pragma unroll
  for (int off=32; off; off>>=1){ s += __shfl_down(s, off); ss += __shfl_down(ss, off); }
  __shared__ float rs[4], rss[4];
  const int lane = threadIdx.x & 63, wv = threadIdx.x >> 6;
  if (lane == 0){ rs[wv] = s; rss[wv] = ss; }
  __syncthreads();
  if (threadIdx.x == 0){
    atomicAdd(&stats[bb*2+0], rs[0]+rs[1]+rs[2]+rs[3]);
    atomicAdd(&stats[bb*2+1], rss[0]+rss[1]+rss[2]+rss[3]);
  }
}

// ---------- K1b: weight transform w[co][ci][3][3] f32 -> wt[tap][co][ci] bf16 ----------
__global__ __launch_bounds__(256) void k_wt(const float* __restrict__ w, u16* __restrict__ wt){
  int e = blockIdx.x*256 + threadIdx.x;   // grid 144 -> 36864 elems
  int tap = e >> 12, co = (e >> 6) & 63, ci = e & 63;
  wt[e] = f2bf(w[(co*64 + ci)*9 + tap]);
}

// ---------- K2: gather tokens, LN, q = normalize(xx @ wqk), v gather (v stored [Bb][ch][sigma(token)]) ----------
__global__ __launch_bounds__(256) void k_qv(const float* __restrict__ x, const float* __restrict__ wqk,
                                            const float* __restrict__ stats,
                                            u16* __restrict__ qb, u16* __restrict__ vb){
  const int Bb = blockIdx.x >> 4;          // 0..127
  const int mt = blockIdx.x & 15;          // token tile (64 tokens)
  const int b = Bb >> 4, fi = (Bb >> 2) & 3, fj = Bb & 3;
  const float inv_n = 1.f/1048576.f;
  const float mu   = stats[2*b] * inv_n;
  const float var  = stats[2*b+1]*inv_n - mu*mu;
  const float rstd = rsqrtf(var + 1e-5f);

  __shared__ float xt[64][68];             // [token][cc], normalized
  __shared__ float wk[64][68];             // [cc][e]  (later reused for v staging)
  __shared__ float red[64][17];
  const int t = threadIdx.x;
  const int m0 = mt << 6;

  #pragma unroll
  for (int i=0;i<16;++i){ int e = t+(i<<8); wk[e>>6][e&63] = wqk[e]; }
  #pragma unroll
  for (int i=0;i<16;++i){
    int e = t+(i<<8); int cc = e>>6, ml = e&63;
    int m = m0 + ml;
    int hh = ((m>>5)<<2)+fi, ww = ((m&31)<<2)+fj;
    xt[ml][cc] = (x[(((b<<6)+cc)<<14)+(hh<<7)+ww] - mu)*rstd;
  }
  __syncthreads();                         // [A]

  const int ty = t>>4, tx = t&15;
  float acc[4][4] = {};
  for (int cc=0; cc<64; ++cc){
    float a0=xt[(ty<<2)+0][cc], a1=xt[(ty<<2)+1][cc], a2=xt[(ty<<2)+2][cc], a3=xt[(ty<<2)+3][cc];
    float b0=wk[cc][(tx<<2)+0], b1=wk[cc][(tx<<2)+1], b2=wk[cc][(tx<<2)+2], b3=wk[cc][(tx<<2)+3];
    acc[0][0]+=a0*b0; acc[0][1]+=a0*b1; acc[0][2]+=a0*b2; acc[0][3]+=a0*b3;
    acc[1][0]+=a1*b0; acc[1][1]+=a1*b1; acc[1][2]+=a1*b2; acc[1][3]+=a1*b3;
    acc[2][0]+=a2*b0; acc[2][1]+=a2*b1; acc[2][2]+=a2*b2; acc[2][3]+=a2*b3;
    acc[3][0]+=a3*b0; acc[3][1]+=a3*b1; acc[3][2]+=a3*b2; acc[3][3]+=a3*b3;
  }
  #pragma unroll
  for (int i=0;i<4;++i){
    float pn = acc[i][0]*acc[i][0]+acc[i][1]*acc[i][1]+acc[i][2]*acc[i][2]+acc[i][3]*acc[i][3];
    red[(ty<<2)+i][tx] = pn;
  }
  __syncthreads();                         // [B] -- all acc/xt reads done
  float inv[4];
  #pragma unroll
  for (int i=0;i<4;++i){
    float s = 0.f;
    #pragma unroll
    for (int k=0;k<16;++k) s += red[(ty<<2)+i][k];
    inv[i] = 1.f / fmaxf(sqrtf(s), 1e-12f);
  }
  // stage normalized q back into xt (safe after [B])
  #pragma unroll
  for (int i=0;i<4;++i)
    #pragma unroll
    for (int j=0;j<4;++j)
      xt[(ty<<2)+i][(tx<<2)+j] = acc[i][j]*inv[i];
  __syncthreads();                         // [C]
  #pragma unroll
  for (int i=0;i<16;++i){
    int e = t+(i<<8); int ml = e>>6, ee = e&63;
    qb[((Bb<<10)+m0+ml)*64 + ee] = f2bf(xt[ml][ee]);
  }
  // v gather -> wk (safe after [B]/[C]); write out TRANSPOSED + sigma-permuted: vb[Bb][ch][m0+sigma(ml)]
  #pragma unroll
  for (int i=0;i<16;++i){
    int e = t+(i<<8); int cc = e>>6, ml = e&63;
    int m = m0 + ml;
    int hh = ((m>>5)<<2)+fi, ww = ((m&31)<<2)+fj;
    wk[ml][cc] = x[(((b<<6)+cc)<<14)+(hh<<7)+ww];
  }
  __syncthreads();                         // [D]
  #pragma unroll
  for (int i=0;i<16;++i){
    int e = t+(i<<8); int cc = e>>6, ml = e&63;
    int nt = ml>>4, ss = (ml>>2)&3, r = ml&3;
    int sig = ((ss + ((nt>>1)<<2))<<3) + ((nt&1)<<2) + r;
    vb[(Bb<<16) + (cc<<10) + m0 + sig] = f2bf(wk[ml][cc]);
  }
}

// ---------- K3: flash attention, transposed-S + in-register P (no P LDS round-trip) ----------
// 512 thr (8 waves), grid 1024, bid%8=batch (XCD swizzle). Each wave owns 16 q-rows;
// K/V staged once per kt for all 8 waves. S^T = mfma(K,Q) -> P in regs (cvt_pk) -> O^T = mfma(V,P^T).
__global__ __launch_bounds__(512) void k_attn(const u16* __restrict__ qb, const u16* __restrict__ vb,
                                              const float* __restrict__ x, u16* __restrict__ apad){
  const int bid = blockIdx.x;              // 0..1023
  const int b   = bid & 7;
  const int rem = bid >> 3;                // 0..127
  const int qtp = rem >> 4;                // 0..7  (128-row q block)
  const int sub = rem & 15;
  const int Bb  = (b<<4) + sub;
  const int fi = (sub>>2)&3, fj = sub&3;
  __shared__ __align__(16) char lds[17664];  // K 8KB | V 8KB ; epilogue os[64][69] f32
  const int KS = 0, VS = 8192;

  const int t = threadIdx.x;
  const int w = t >> 6, lane = t & 63;
  const int lrow = lane & 15, lk = lane >> 4;

  const u16* qB = qb + (Bb<<16);
  const u16* vB = vb + (Bb<<16);

  // Q fragments for this wave's 16 rows (B-operand: col=lane&15=q, k=ch)
  const u16* qrp = qB + ((qtp<<7) + (w<<4) + lrow)*64;
  const s16x8 qf0 = *(const s16x8*)(qrp + (lk<<3));
  const s16x8 qf1 = *(const s16x8*)(qrp + 32 + (lk<<3));

  f32x4 o_acc[4] = {};                     // O^T: lane holds q=lrow, ch=16nt+4lk+r
  float lp = 0.f;                          // running sum of P over this lane's 16 keys

  for (int kt=0; kt<16; ++kt){
    __syncthreads();                       // protect ks/vs from previous iteration's readers
    {
      int row = t >> 3, slot = t & 7;      // 512 threads: one 16B chunk each for K and V
      uint4 kv = *(const uint4*)(qB + ((kt<<6)+row)*64 + (slot<<3));
      *(uint4*)(lds + KS + row*128 + ((slot ^ (row&7))<<4)) = kv;
      uint4 vv = *(const uint4*)(vB + (row<<10) + (kt<<6) + (slot<<3));
      *(uint4*)(lds + VS + row*128 + ((slot ^ (row&7))<<4)) = vv;
    }
    __syncthreads();

    // S^T = K Q^T per 16-key block nt; P packed to bf16 in registers
    u32x4 pa, pb;
    #pragma unroll
    for (int nt=0; nt<4; ++nt){
      int key = (nt<<4) + lrow;
      const char* kb = lds + KS + key*128;
      s16x8 kf0 = *(const s16x8*)(kb + ((lk     ^ (key&7))<<4));
      s16x8 kf1 = *(const s16x8*)(kb + (((4+lk) ^ (key&7))<<4));
      f32x4 sa = {};
      sa = __builtin_amdgcn_mfma_f32_16x16x32_bf16(kf0, qf0, sa, 0,0,0);
      sa = __builtin_amdgcn_mfma_f32_16x16x32_bf16(kf1, qf1, sa, 0,0,0);
      // sa[r] = S^T[key=16nt+4lk+r][q=lrow]
      float p0 = __expf(sa[0]*0.125f), p1 = __expf(sa[1]*0.125f);
      float p2 = __expf(sa[2]*0.125f), p3 = __expf(sa[3]*0.125f);
      lp += (p0+p1)+(p2+p3);
      u32 lo, hi;
      asm("v_cvt_pk_bf16_f32 %0, %1, %2" : "=v"(lo) : "v"(p0), "v"(p1));
      asm("v_cvt_pk_bf16_f32 %0, %1, %2" : "=v"(hi) : "v"(p2), "v"(p3));
      if (nt==0){ pa[0]=lo; pa[1]=hi; }
      else if (nt==1){ pa[2]=lo; pa[3]=hi; }
      else if (nt==2){ pb[0]=lo; pb[1]=hi; }
      else          { pb[2]=lo; pb[3]=hi; }
    }
    s16x8 pf0 = as_s16x8(pa), pf1 = as_s16x8(pb);

    // O^T += V P^T  (A=V rows=ch, B=P^T cols=q; V slot keys match P frag keys via sigma)
    #pragma unroll
    for (int nt=0; nt<4; ++nt){
      int ch = (nt<<4) + lrow;
      const char* vbp = lds + VS + ch*128;
      s16x8 vf0 = *(const s16x8*)(vbp + ((lk     ^ (ch&7))<<4));
      s16x8 vf1 = *(const s16x8*)(vbp + (((4+lk) ^ (ch&7))<<4));
      o_acc[nt] = __builtin_amdgcn_mfma_f32_16x16x32_bf16(vf0, pf0, o_acc[nt], 0,0,0);
      o_acc[nt] = __builtin_amdgcn_mfma_f32_16x16x32_bf16(vf1, pf1, o_acc[nt], 0,0,0);
    }
  }

  // row sum for q=lrow: in-lane 16 keys + reduce over the 4 lk-lanes (lane bits 4,5)
  {
    float s = lp;
    s += __shfl_xor(s, 16); s += __shfl_xor(s, 32);
    lp = 1.f / s;
  }

  // epilogue: two 64-row halves through os[64][69] f32 (17664B, overlays K/V)
  float* os = (float*)lds;
  #pragma unroll
  for (int half=0; half<2; ++half){
    __syncthreads();                       // half0: ks/vs reads done; half1: prev os reads done
    if ((w>>2) == half){
      int ql = ((w&3)<<4) + lrow;
      #pragma unroll
      for (int nt=0;nt<4;++nt)
        #pragma unroll
        for (int r=0;r<4;++r)
          os[ql*69 + (nt<<4)+(lk<<2)+r] = o_acc[nt][r]*lp;
    }
    __syncthreads();
    const int m0 = (qtp<<7) + (half<<6);
    // phase 1: residual add (token-fastest -> x reads L2-local)
    #pragma unroll
    for (int i=0;i<8;++i){
      int e = t + (i<<9);                  // 4096 = 64ch * 64tok
      int cc = e>>6, ml = e&63;
      int m = m0 + ml;
      int hh = ((m>>5)<<2)+fi, ww = ((m&31)<<2)+fj;
      os[ml*69 + cc] += x[(((b<<6)+cc)<<14) + (hh<<7) + ww];
    }
    __syncthreads();
    // phase 2: coalesced channel-last padded write
    #pragma unroll
    for (int i=0;i<8;++i){
      int e = t + (i<<9);
      int ml = e>>6, cc = e&63;
      int m = m0 + ml;
      int hh = ((m>>5)<<2)+fi, ww = ((m&31)<<2)+fj;
      apad[((b*132 + hh+2)*132 + ww+2)*64 + cc] = f2bf(os[ml*69 + cc]);
    }
  }
}

// ---------- K4/K5: 3x3 dil-2 conv via MFMA implicit GEMM, channel-last padded, no LDS ----------
// 1D grid 2048, bid%8 = batch (XCD-swizzled: each batch's input L2-resident on one XCD).
__global__ __launch_bounds__(256) void k_conv3m(const u16* __restrict__ in, const u16* __restrict__ wt,
                                                const float* __restrict__ bias, u16* __restrict__ outp){
  const int bid = blockIdx.x;
  const int b   = bid & 7;
  const int r   = bid >> 3;                // 0..255
  const int h   = r & 127;
  const int seg = r >> 7;                  // 0..1
  const int t = threadIdx.x;
  const int wv = t >> 6, lane = t & 63;
  const int lrow = lane & 15, lk = lane >> 4;
  const int co0 = wv << 4;
  const int w0 = seg << 6;

  s16x8 A[9][2];
  #pragma unroll
  for (int tap=0; tap<9; ++tap)
    #pragma unroll
    for (int hf=0; hf<2; ++hf)
      A[tap][hf] = *(const s16x8*)(wt + (((tap<<6) + co0 + lrow)<<6) + (hf<<5) + (lk<<3));

  float4 b4 = *(const float4*)&bias[co0 + (lk<<2)];
  f32x4 binit = {b4.x, b4.y, b4.z, b4.w};
  f32x4 acc[4] = {binit, binit, binit, binit};

  const int base_b = b * (132*132);        // pixel-index base
  #pragma unroll
  for (int dh=0; dh<3; ++dh){
    const u16* rowp = in + ((base_b + (h + (dh<<1))*132)<<6);
    #pragma unroll
    for (int dw=0; dw<3; ++dw){
      #pragma unroll
      for (int hf=0; hf<2; ++hf){
        #pragma unroll
        for (int pt=0; pt<4; ++pt){
          int wp = w0 + (pt<<4) + lrow + (dw<<1);
          s16x8 B = *(const s16x8*)(rowp + (wp<<6) + (hf<<5) + (lk<<3));
          acc[pt] = __builtin_amdgcn_mfma_f32_16x16x32_bf16(A[dh*3+dw][hf], B, acc[pt], 0,0,0);
        }
      }
    }
  }

  #pragma unroll
  for (int pt=0; pt<4; ++pt){
    int wp = w0 + (pt<<4) + lrow + 2;
    u16* op = outp + ((base_b + (h+2)*132 + wp)<<6) + co0 + (lk<<2);
    ushort4 o4;
    o4.x = f2bf(fmaxf(acc[pt][0], 0.f));
    o4.y = f2bf(fmaxf(acc[pt][1], 0.f));
    o4.z = f2bf(fmaxf(acc[pt][2], 0.f));
    o4.w = f2bf(fmaxf(acc[pt][3], 0.f));
    *(ushort4*)op = o4;
  }
}

// ---------- K6: 1x1 conv + residual with x (y2 padded ch-last in, f32 out) ----------
__global__ __launch_bounds__(256) void k_conv1x1(const u16* __restrict__ y2, const float* __restrict__ w3,
                                                 const float* __restrict__ b3, const float* __restrict__ x,
                                                 float* __restrict__ out){
  const int b  = blockIdx.x >> 6;
  const int p0 = (blockIdx.x & 63) << 8;   // 256 pixels per block
  __shared__ u16  ys[256][68];             // [px][ci]
  __shared__ float w3s[64][68];            // [ci][co]
  __shared__ float bs[64];
  const int t = threadIdx.x;
  #pragma unroll
  for (int i=0;i<16;++i){ int e = t+(i<<8); w3s[e & 63][e >> 6] = w3[e]; }
  if (t < 64) bs[t] = b3[t];
  #pragma unroll
  for (int i=0;i<64;++i){
    int e = t + (i<<8);
    int px = e >> 6, ci = e & 63;
    int pg = p0 + px; int hh = pg >> 7, ww = pg & 127;
    ys[px][ci] = y2[((b*132 + hh+2)*132 + ww+2)*64 + ci];
  }
  __syncthreads();
  const int cog = (t >> 6) << 4;           // co base: 0/16/32/48 (uniform per wave)
  const int pl  = t & 63;                  // pixels pl, pl+64, pl+128, pl+192
  float acc[16][4];
  #pragma unroll
  for (int c=0;c<16;++c){
    float bvv = bs[cog+c];
    acc[c][0]=bvv; acc[c][1]=bvv; acc[c][2]=bvv; acc[c][3]=bvv;
  }
  for (int c4=0;c4<64;c4+=4){
    float yv[4][4];
    #pragma unroll
    for (int p=0;p<4;++p){
      ushort4 u = *(const ushort4*)&ys[pl + (p<<6)][c4];
      yv[p][0]=bf2f(u.x); yv[p][1]=bf2f(u.y); yv[p][2]=bf2f(u.z); yv[p][3]=bf2f(u.w);
    }
    #pragma unroll
    for (int cq=0;cq<4;++cq){
      float4 w0 = *(const float4*)&w3s[c4+0][cog+(cq<<2)];
      float4 w1 = *(const float4*)&w3s[c4+1][cog+(cq<<2)];
      float4 w2 = *(const float4*)&w3s[c4+2][cog+(cq<<2)];
      float4 w3v = *(const float4*)&w3s[c4+3][cog+(cq<<2)];
      #pragma unroll
      for (int p=0;p<4;++p){
        acc[(cq<<2)+0][p] += yv[p][0]*w0.x + yv[p][1]*w1.x + yv[p][2]*w2.x + yv[p][3]*w3v.x;
        acc[(cq<<2)+1][p] += yv[p][0]*w0.y + yv[p][1]*w1.y + yv[p][2]*w2.y + yv[p][3]*w3v.y;
        acc[(cq<<2)+2][p] += yv[p][0]*w0.z + yv[p][1]*w1.z + yv[p][2]*w2.z + yv[p][3]*w3v.z;
        acc[(cq<<2)+3][p] += yv[p][0]*w0.w + yv[p][1]*w1.w + yv[p][2]*w2.w + yv[p][3]*w3v.w;
      }
    }
  }
  #pragma unroll
  for (int c=0;c<16;++c){
    int base = (((b<<6)+cog+c)<<14) + p0 + pl;
    #pragma unroll
    for (int p=0;p<4;++p){
      int gi = base + (p<<6);
      out[gi] = acc[c][p] + x[gi];
    }
  }
}

// ---------- launch ----------
extern "C" void kernel_launch(void* const* d_in, const int* in_sizes, int n_in,
                              void* d_out, int out_size, void* d_ws, size_t ws_size,
                              hipStream_t stream){
  const float* x   = (const float*)d_in[0];
  const float* wqk = (const float*)d_in[1];
  const float* w1  = (const float*)d_in[2];
  const float* b1  = (const float*)d_in[3];
  const float* w2  = (const float*)d_in[4];
  const float* b2  = (const float*)d_in[5];
  const float* w3  = (const float*)d_in[6];
  const float* b3  = (const float*)d_in[7];
  float* out = (float*)d_out;

  // ws layout (51.5 MB):
  //   stats 256B | qb 16MB | vb 16MB | apad 17.84MB | wt1 72KB | wt2 72KB
  //   y1 aliases qb+vb (dead after attn); y2 aliases apad (a dead after conv1)
  float* stats = (float*)d_ws;
  u16* qb   = (u16*)((char*)d_ws + 256);
  u16* vb   = qb + 8388608;
  u16* apad = vb + 8388608;                // 8*132*132*64 = 8,921,088 elems
  u16* y1   = qb;
  u16* y2   = apad;
  u16* wt1  = apad + 8921088;
  u16* wt2  = wt1 + 36864;

  hipMemsetAsync(stats, 0, 64, stream);
  k_wt<<<144, 256, 0, stream>>>(w1, wt1);
  k_wt<<<144, 256, 0, stream>>>(w2, wt2);
  k_lnstats<<<1024, 256, 0, stream>>>(x, stats);
  k_qv     <<<2048, 256, 0, stream>>>(x, wqk, stats, qb, vb);
  hipMemsetAsync(apad, 0, 17842176, stream);                    // zero a borders
  k_attn   <<<1024, 512, 0, stream>>>(qb, vb, x, apad);
  hipMemsetAsync(y1, 0, 17842176, stream);                      // zero y1 borders (qb/vb dead)
  k_conv3m <<<2048, 256, 0, stream>>>(apad, wt1, b1, y1);
  k_conv3m <<<2048, 256, 0, stream>>>(y1, wt2, b2, y2);         // y2 = apad region
  k_conv1x1<<<512, 256, 0, stream>>>(y2, w3, b3, x, out);
}